// Round 14
// baseline (208.590 us; speedup 1.0000x reference)
//
#include <hip/hip_runtime.h>

// TangentSpaceLoss: loss = (1/B^2) sum_ij softmax_j(E E^T)_ij * ||v_i - v_j||^2
// B=8192, G=512, D=64.
//
// R13 post-mortem: k_mega 81us, all pipes <28% => latency-bound at ~8.6
// waves/CU; non-mega residue = k_prep + k_red + ~3 launch overheads. R14:
// (1) __launch_bounds__(256,4): gacc(64 AGPR) + <=64 VGPR epilogue. The
//     R11 spill at (256,4) was WITH bh hoisted (~76 VGPR needed); B frags
//     are now RELOADED per (im,jn) from L1 (+24 hot loads/wave) to fit.
//     Spill tripwire: WRITE_SIZE >> 14 MB means the diet failed.
// (2) k_red merged into k_mega: completion counter; last block re-reads
//     Z/num via atomicAdd(p,0.f) (fresh device-scope reads, no stale L1)
//     and does the 8192-row reduce + final write. 2 launches total.
//   G: fp8 e4m3 MFMA K=512 (VF8 frag-linear, 16B/lane wave-loads, no LDS
//      staging, no barriers in the K-loop)
//   S: fp16 MFMA (EFh frag-linear), fused epilogue w/ ballot-skip,
//      LDS-plane cross-wave combine, direct Z/num atomics w/ zero-skip.
// Selection: s > min(ne_i,ne_j)-32 (safe superset). Softmax shift ne_i;
// diagonal w=1, wd=0 -> Z preinit 1 (k_prep). XCD band swizzle (2080=8*260).
//
// VF8: [rt 512][c 8][m 16][q 4][kc 2][8B]; lane (m,quad) reads 16B at
// m*64+quad*16 (bytes 0-7 = K-chunk kc0, 8-15 = kc1).
// EFh: [rt 512][kc 2][m 16][k' 32] halfs.

#define SEL_T 32.0f

typedef _Float16 half8 __attribute__((ext_vector_type(8)));
typedef float    f32x4 __attribute__((ext_vector_type(4)));
typedef long     l2t   __attribute__((ext_vector_type(2)));

#define MFMA16(a, b, c) __builtin_amdgcn_mfma_f32_16x16x32_f16(a, b, c, 0, 0, 0)
#define MFMA8(a, b, c)  __builtin_amdgcn_mfma_f32_16x16x32_fp8_fp8(a, b, c, 0, 0, 0)

// ---------------- K1: norms + fp8 V + fp16 E layouts + Z/num init -------
__global__ __launch_bounds__(256) void k_prep(
    const float* __restrict__ V, const float* __restrict__ E,
    float* __restrict__ n, float* __restrict__ ne,
    float* __restrict__ Z, float* __restrict__ num,
    unsigned char* __restrict__ VF8, _Float16* __restrict__ EFh,
    unsigned* __restrict__ cnt) {
    int rt = blockIdx.x;                       // 512 row-tiles of 16 rows
    int tid = threadIdx.x, wave = tid >> 6, lane = tid & 63;
    if (rt == 0 && tid == 0) *cnt = 0;
    int m = lane >> 2, q = lane & 3;
    int row = rt * 16 + m;
    const float* vr = V + (size_t)row * 512;
    float sn = 0.f;
#pragma unroll
    for (int it = 0; it < 2; ++it) {
        int c = wave + it * 4;                 // K-chunk of 64
        const float4* p0 = (const float4*)(vr + c * 64 + q * 8);
        const float4* p1 = (const float4*)(vr + c * 64 + 32 + q * 8);
        float4 a0 = p0[0], a1 = p0[1], b0 = p1[0], b1 = p1[1];
        int w0 = 0, w1 = 0, w2 = 0, w3 = 0;
        w0 = __builtin_amdgcn_cvt_pk_fp8_f32(a0.x, a0.y, w0, false);
        w0 = __builtin_amdgcn_cvt_pk_fp8_f32(a0.z, a0.w, w0, true);
        w1 = __builtin_amdgcn_cvt_pk_fp8_f32(a1.x, a1.y, w1, false);
        w1 = __builtin_amdgcn_cvt_pk_fp8_f32(a1.z, a1.w, w1, true);
        w2 = __builtin_amdgcn_cvt_pk_fp8_f32(b0.x, b0.y, w2, false);
        w2 = __builtin_amdgcn_cvt_pk_fp8_f32(b0.z, b0.w, w2, true);
        w3 = __builtin_amdgcn_cvt_pk_fp8_f32(b1.x, b1.y, w3, false);
        w3 = __builtin_amdgcn_cvt_pk_fp8_f32(b1.z, b1.w, w3, true);
        uint4 o;
        o.x = (unsigned)w0; o.y = (unsigned)w1;
        o.z = (unsigned)w2; o.w = (unsigned)w3;
        *(uint4*)(VF8 + (((size_t)rt * 8 + c) << 10) + lane * 16) = o;
        sn += a0.x*a0.x + a0.y*a0.y + a0.z*a0.z + a0.w*a0.w
            + a1.x*a1.x + a1.y*a1.y + a1.z*a1.z + a1.w*a1.w
            + b0.x*b0.x + b0.y*b0.y + b0.z*b0.z + b0.w*b0.w
            + b1.x*b1.x + b1.y*b1.y + b1.z*b1.z + b1.w*b1.w;
    }
    __shared__ float sred[4][64];
    sred[wave][lane] = sn;
    __syncthreads();
    if (tid < 16) {
        float s = 0.f;
#pragma unroll
        for (int w = 0; w < 4; ++w)
#pragma unroll
            for (int qq = 0; qq < 4; ++qq) s += sred[w][tid * 4 + qq];
        int rr = rt * 16 + tid;
        n[rr] = s;
        Z[rr] = 1.0f;                          // diagonal w=1, wd=0
        num[rr] = 0.0f;
    }
    // E: threads 0..127: rl = t>>3, u = t&7, k in [u*8, u*8+8)
    if (tid < 128) {
        int rl = tid >> 3, u = tid & 7;
        int erow = rt * 16 + rl;
        const float4* er = (const float4*)(E + (size_t)erow * 64);
        float4 x0 = er[u * 2], x1 = er[u * 2 + 1];
        float xf[8] = {x0.x, x0.y, x0.z, x0.w, x1.x, x1.y, x1.z, x1.w};
        half8 h;
        float se = 0.f;
#pragma unroll
        for (int k = 0; k < 8; ++k) {
            h[k] = (_Float16)xf[k];
            se += xf[k] * xf[k];
        }
        int kc = u >> 2, qq = u & 3;
        *(half8*)(EFh + ((size_t)rt * 2 + kc) * 512 + rl * 32 + qq * 8) = h;
        se += __shfl_xor(se, 1, 64);
        se += __shfl_xor(se, 2, 64);
        se += __shfl_xor(se, 4, 64);
        if (u == 0) ne[erow] = se;
    }
}

// ---------------- K2: zero-LDS gather tile kernel + final reduce --------
// 256 thr = 4 waves in 2x2 grid; wave tile 64x64 = 4x4 MFMA tiles.
__global__ __launch_bounds__(256, 4) void k_mega(
    const unsigned char* __restrict__ VF8, const _Float16* __restrict__ EFh,
    const float* __restrict__ ne, const float* __restrict__ nrm,
    float* __restrict__ Z, float* __restrict__ num,
    unsigned* __restrict__ cnt, float* __restrict__ out) {
    // XCD band swizzle + triangular decode: blk -> (bx <= by)
    int blk0 = blockIdx.x;
    int blk = (blk0 & 7) * 260 + (blk0 >> 3);
    int by = (int)((sqrtf(8.f * (float)blk + 1.f) - 1.f) * 0.5f);
    while ((by + 1) * (by + 2) / 2 <= blk) ++by;
    while (by * (by + 1) / 2 > blk) --by;
    int bx = blk - by * (by + 1) / 2;
    int i0 = bx << 7, j0 = by << 7;
    bool diag = (bx == by);

    __shared__ float sNeI[128], sNeJ[128], sNI[128], sNJ[128];
    __shared__ __align__(16) float scr[1024];
    __shared__ unsigned lastFlag;

    int tid = threadIdx.x;
    if (tid < 128) { sNeI[tid] = ne[i0 + tid]; sNI[tid] = nrm[i0 + tid]; }
    else { sNeJ[tid - 128] = ne[j0 + tid - 128]; sNJ[tid - 128] = nrm[j0 + tid - 128]; }
    __syncthreads();

    int wave = tid >> 6, lane = tid & 63;
    int m = lane & 15, quad = lane >> 4;
    int wi = wave & 1, wj = wave >> 1;
    int rtA = (i0 >> 4) + wi * 4;            // + im
    int rtB = (j0 >> 4) + wj * 4;            // + jn
    size_t loH = (size_t)(m * 32 + quad * 8);   // halfs (E frags)
    size_t loB = (size_t)(m * 64 + quad * 16);  // bytes (V fp8 frags)

    // ---- G phase: K=512, 8 chunks of 64; fp8, no LDS, no barriers ----
    f32x4 gacc[4][4] = {};
    for (int c = 0; c < 8; ++c) {
        l2t a[4], b[4];
#pragma unroll
        for (int im = 0; im < 4; ++im)
            a[im] = *(const l2t*)(VF8 + (((size_t)(rtA + im) * 8 + c) << 10) + loB);
#pragma unroll
        for (int jn = 0; jn < 4; ++jn)
            b[jn] = *(const l2t*)(VF8 + (((size_t)(rtB + jn) * 8 + c) << 10) + loB);
#pragma unroll
        for (int jn = 0; jn < 4; ++jn)
#pragma unroll
            for (int im = 0; im < 4; ++im) {
                gacc[im][jn] = MFMA8(a[im][0], b[jn][0], gacc[im][jn]);
                gacc[im][jn] = MFMA8(a[im][1], b[jn][1], gacc[im][jn]);
            }
    }

    // ---- fused S phase + epilogue (B frags reloaded per (im,jn): L1-hot,
    //      keeps VGPR count under the (256,4) 64-VGPR budget) ----
    float zj[4] = {}, nj_[4] = {};
#pragma unroll
    for (int im = 0; im < 4; ++im) {
        size_t ab = (size_t)(rtA + im) * 2 * 512 + loH;
        half8 ah0 = *(const half8*)(EFh + ab);
        half8 ah1 = *(const half8*)(EFh + ab + 512);
        f32x4 zi4 = {0.f, 0.f, 0.f, 0.f};
        f32x4 ni4 = {0.f, 0.f, 0.f, 0.f};
#pragma unroll
        for (int jn = 0; jn < 4; ++jn) {
            size_t bb = (size_t)(rtB + jn) * 2 * 512 + loH;
            half8 bh0 = *(const half8*)(EFh + bb);
            half8 bh1 = *(const half8*)(EFh + bb + 512);
            f32x4 acc = {0.f, 0.f, 0.f, 0.f};
            acc = MFMA16(ah0, bh0, acc);
            acc = MFMA16(ah1, bh1, acc);
            int jl = (wj << 6) + jn * 16 + m;
            int jg = j0 + jl;
            float nej = sNeJ[jl], nnj = sNJ[jl];
            f32x4 g4 = gacc[im][jn];
            bool p[4];
            bool anyp = false;
#pragma unroll
            for (int r = 0; r < 4; ++r) {
                int il = (wi << 6) + im * 16 + quad * 4 + r;
                int ig = i0 + il;
                float nei = sNeI[il];
                p[r] = (acc[r] > fminf(nei, nej) - SEL_T) && (!diag || ig < jg);
                anyp |= p[r];
            }
            if (__builtin_amdgcn_ballot_w64(anyp)) {   // wave-uniform skip
#pragma unroll
                for (int r = 0; r < 4; ++r) {
                    if (p[r]) {
                        int il = (wi << 6) + im * 16 + quad * 4 + r;
                        float nei = sNeI[il], nni = sNI[il];
                        float s = acc[r];
                        float wiw = __expf(s - nei);
                        float wjw = __expf(s - nej);
                        float wd = nni + nnj - 2.f * g4[r];
                        zi4[r] += wiw;  ni4[r] += wiw * wd;
                        zj[jn] += wjw;  nj_[jn] += wjw * wd;
                    }
                }
            }
        }
        // i-side: reduce over 16 m-lanes, write wj-plane
#pragma unroll
        for (int msk = 1; msk < 16; msk <<= 1) {
#pragma unroll
            for (int r = 0; r < 4; ++r) {
                zi4[r] += __shfl_xor(zi4[r], msk, 64);
                ni4[r] += __shfl_xor(ni4[r], msk, 64);
            }
        }
        if (m == 0) {
            int row0 = (wi << 6) + im * 16 + quad * 4;
            *(f32x4*)(scr + (wj << 7) + row0)       = zi4;
            *(f32x4*)(scr + 256 + (wj << 7) + row0) = ni4;
        }
    }
    // j-side: reduce over quads, write wi-plane
#pragma unroll
    for (int msk = 16; msk < 64; msk <<= 1) {
#pragma unroll
        for (int jn = 0; jn < 4; ++jn) {
            zj[jn]  += __shfl_xor(zj[jn],  msk, 64);
            nj_[jn] += __shfl_xor(nj_[jn], msk, 64);
        }
    }
    if (quad == 0) {
#pragma unroll
        for (int jn = 0; jn < 4; ++jn) {
            int jl = (wj << 6) + jn * 16 + m;
            scr[512 + (wi << 7) + jl] = zj[jn];
            scr[768 + (wi << 7) + jl] = nj_[jn];
        }
    }
    __syncthreads();
    // fold planes -> direct device atomics (zero-skip for empty rows)
    if (tid < 128) {
        float az = scr[tid]       + scr[128 + tid];
        float an = scr[256 + tid] + scr[384 + tid];
        if (az != 0.f || an != 0.f) {
            atomicAdd(Z + i0 + tid,   az);
            atomicAdd(num + i0 + tid, an);
        }
    } else {
        int cidx = tid - 128;
        float az = scr[512 + cidx] + scr[640 + cidx];
        float an = scr[768 + cidx] + scr[896 + cidx];
        if (az != 0.f || an != 0.f) {
            atomicAdd(Z + j0 + cidx,   az);
            atomicAdd(num + j0 + cidx, an);
        }
    }

    // ---- completion counter: last block does the final reduce ----
    __syncthreads();                 // all atomics drained (vmcnt(0) @ barrier)
    if (tid == 0) {
        __threadfence();
        unsigned old = atomicAdd(cnt, 1u);
        lastFlag = (old == 2079u) ? 1u : 0u;
    }
    __syncthreads();
    if (lastFlag) {
        double acc = 0.0;
#pragma unroll
        for (int k = 0; k < 32; ++k) {
            int r = (k << 8) + tid;
            float z  = atomicAdd(Z + r, 0.0f);     // fresh device-scope read
            float nv = atomicAdd(num + r, 0.0f);
            acc += (double)nv / (double)z;
        }
        double* sd = (double*)scr;
        sd[tid] = acc;
        __syncthreads();
        for (int st = 128; st > 0; st >>= 1) {
            if (tid < st) sd[tid] += sd[tid + st];
            __syncthreads();
        }
        if (tid == 0) out[0] = (float)(sd[0] / 67108864.0);   // / B^2
    }
}

// ---------------- host launcher -----------------------------------------
extern "C" void kernel_launch(void* const* d_in, const int* in_sizes, int n_in,
                              void* d_out, int out_size, void* d_ws, size_t ws_size,
                              hipStream_t stream) {
    const float* V = (const float*)d_in[0];   // [8192, 512] f32
    const float* E = (const float*)d_in[1];   // [8192, 64]  f32
    float* out = (float*)d_out;
    char* ws = (char*)d_ws;

    float*         n_   = (float*)(ws + 0);            // 32 KB
    float*         ne   = (float*)(ws + 32768);        // 32 KB
    float*         Z    = (float*)(ws + 65536);        // 32 KB (init 1 in k_prep)
    float*         num  = (float*)(ws + 98304);        // 32 KB (init 0 in k_prep)
    unsigned char* VF8  = (unsigned char*)(ws + 131072);// 4 MB fp8 V frags
    _Float16*      EFh  = (_Float16*)(ws + 4325376);   // 1 MB
    unsigned*      cnt  = (unsigned*)(ws + 5373952);   // 4 B

    k_prep<<<512, 256, 0, stream>>>(V, E, n_, ne, Z, num, VF8, EFh, cnt);
    k_mega<<<2080, 256, 0, stream>>>(VF8, EFh, ne, n_, Z, num, cnt, out);
}

// Round 15
// 183.350 us; speedup vs baseline: 1.1377x; 1.1377x over previous
//
#include <hip/hip_runtime.h>

// TangentSpaceLoss: loss = (1/B^2) sum_ij softmax_j(E E^T)_ij * ||v_i - v_j||^2
// B=8192, G=512, D=64.
//
// R14 post-mortem: (256,4) spilled AGAIN (WRITE 62 MB, k_mega 150us) — a
// 4x4 wave tile + fused S needs ~84 VGPRs; 64 isn't enough no matter the
// reload tricks. (256,3) is the pareto point for this design (R13: 81us,
// WRITE 14 MB, no spill). R15 = R13's k_mega config (256,3, bh hoisted)
// + R14's one good idea: merged last-block final reduce (saves the k_red
// launch; completion-counter path verified correct in R14).
//   G: fp8 e4m3 MFMA K=512 (VF8 frag-linear, 16B/lane wave-loads, no LDS
//      staging, no barriers in the K-loop)
//   S: fp16 MFMA (EFh frag-linear, B-frags hoisted), fused epilogue w/
//      ballot-skip, LDS-plane cross-wave combine, direct Z/num atomics.
// Selection: s > min(ne_i,ne_j)-32 (safe superset). Softmax shift ne_i;
// diagonal w=1, wd=0 -> Z preinit 1 (k_prep). XCD band swizzle (2080=8*260).
//
// VF8: [rt 512][c 8][m 16][q 4][kc 2][8B]; lane (m,quad) reads 16B at
// m*64+quad*16 (bytes 0-7 = K-chunk kc0, 8-15 = kc1).
// EFh: [rt 512][kc 2][m 16][k' 32] halfs.

#define SEL_T 32.0f

typedef _Float16 half8 __attribute__((ext_vector_type(8)));
typedef float    f32x4 __attribute__((ext_vector_type(4)));
typedef long     l2t   __attribute__((ext_vector_type(2)));

#define MFMA16(a, b, c) __builtin_amdgcn_mfma_f32_16x16x32_f16(a, b, c, 0, 0, 0)
#define MFMA8(a, b, c)  __builtin_amdgcn_mfma_f32_16x16x32_fp8_fp8(a, b, c, 0, 0, 0)

// ---------------- K1: norms + fp8 V + fp16 E layouts + Z/num init -------
__global__ __launch_bounds__(256) void k_prep(
    const float* __restrict__ V, const float* __restrict__ E,
    float* __restrict__ n, float* __restrict__ ne,
    float* __restrict__ Z, float* __restrict__ num,
    unsigned char* __restrict__ VF8, _Float16* __restrict__ EFh,
    unsigned* __restrict__ cnt) {
    int rt = blockIdx.x;                       // 512 row-tiles of 16 rows
    int tid = threadIdx.x, wave = tid >> 6, lane = tid & 63;
    if (rt == 0 && tid == 0) *cnt = 0;
    int m = lane >> 2, q = lane & 3;
    int row = rt * 16 + m;
    const float* vr = V + (size_t)row * 512;
    float sn = 0.f;
#pragma unroll
    for (int it = 0; it < 2; ++it) {
        int c = wave + it * 4;                 // K-chunk of 64
        const float4* p0 = (const float4*)(vr + c * 64 + q * 8);
        const float4* p1 = (const float4*)(vr + c * 64 + 32 + q * 8);
        float4 a0 = p0[0], a1 = p0[1], b0 = p1[0], b1 = p1[1];
        int w0 = 0, w1 = 0, w2 = 0, w3 = 0;
        w0 = __builtin_amdgcn_cvt_pk_fp8_f32(a0.x, a0.y, w0, false);
        w0 = __builtin_amdgcn_cvt_pk_fp8_f32(a0.z, a0.w, w0, true);
        w1 = __builtin_amdgcn_cvt_pk_fp8_f32(a1.x, a1.y, w1, false);
        w1 = __builtin_amdgcn_cvt_pk_fp8_f32(a1.z, a1.w, w1, true);
        w2 = __builtin_amdgcn_cvt_pk_fp8_f32(b0.x, b0.y, w2, false);
        w2 = __builtin_amdgcn_cvt_pk_fp8_f32(b0.z, b0.w, w2, true);
        w3 = __builtin_amdgcn_cvt_pk_fp8_f32(b1.x, b1.y, w3, false);
        w3 = __builtin_amdgcn_cvt_pk_fp8_f32(b1.z, b1.w, w3, true);
        uint4 o;
        o.x = (unsigned)w0; o.y = (unsigned)w1;
        o.z = (unsigned)w2; o.w = (unsigned)w3;
        *(uint4*)(VF8 + (((size_t)rt * 8 + c) << 10) + lane * 16) = o;
        sn += a0.x*a0.x + a0.y*a0.y + a0.z*a0.z + a0.w*a0.w
            + a1.x*a1.x + a1.y*a1.y + a1.z*a1.z + a1.w*a1.w
            + b0.x*b0.x + b0.y*b0.y + b0.z*b0.z + b0.w*b0.w
            + b1.x*b1.x + b1.y*b1.y + b1.z*b1.z + b1.w*b1.w;
    }
    __shared__ float sred[4][64];
    sred[wave][lane] = sn;
    __syncthreads();
    if (tid < 16) {
        float s = 0.f;
#pragma unroll
        for (int w = 0; w < 4; ++w)
#pragma unroll
            for (int qq = 0; qq < 4; ++qq) s += sred[w][tid * 4 + qq];
        int rr = rt * 16 + tid;
        n[rr] = s;
        Z[rr] = 1.0f;                          // diagonal w=1, wd=0
        num[rr] = 0.0f;
    }
    // E: threads 0..127: rl = t>>3, u = t&7, k in [u*8, u*8+8)
    if (tid < 128) {
        int rl = tid >> 3, u = tid & 7;
        int erow = rt * 16 + rl;
        const float4* er = (const float4*)(E + (size_t)erow * 64);
        float4 x0 = er[u * 2], x1 = er[u * 2 + 1];
        float xf[8] = {x0.x, x0.y, x0.z, x0.w, x1.x, x1.y, x1.z, x1.w};
        half8 h;
        float se = 0.f;
#pragma unroll
        for (int k = 0; k < 8; ++k) {
            h[k] = (_Float16)xf[k];
            se += xf[k] * xf[k];
        }
        int kc = u >> 2, qq = u & 3;
        *(half8*)(EFh + ((size_t)rt * 2 + kc) * 512 + rl * 32 + qq * 8) = h;
        se += __shfl_xor(se, 1, 64);
        se += __shfl_xor(se, 2, 64);
        se += __shfl_xor(se, 4, 64);
        if (u == 0) ne[erow] = se;
    }
}

// ---------------- K2: zero-LDS gather tile kernel + final reduce --------
// 256 thr = 4 waves in 2x2 grid; wave tile 64x64 = 4x4 MFMA tiles.
__global__ __launch_bounds__(256, 3) void k_mega(
    const unsigned char* __restrict__ VF8, const _Float16* __restrict__ EFh,
    const float* __restrict__ ne, const float* __restrict__ nrm,
    float* __restrict__ Z, float* __restrict__ num,
    unsigned* __restrict__ cnt, float* __restrict__ out) {
    // XCD band swizzle + triangular decode: blk -> (bx <= by)
    int blk0 = blockIdx.x;
    int blk = (blk0 & 7) * 260 + (blk0 >> 3);
    int by = (int)((sqrtf(8.f * (float)blk + 1.f) - 1.f) * 0.5f);
    while ((by + 1) * (by + 2) / 2 <= blk) ++by;
    while (by * (by + 1) / 2 > blk) --by;
    int bx = blk - by * (by + 1) / 2;
    int i0 = bx << 7, j0 = by << 7;
    bool diag = (bx == by);

    __shared__ float sNeI[128], sNeJ[128], sNI[128], sNJ[128];
    __shared__ __align__(16) float scr[1024];
    __shared__ unsigned lastFlag;

    int tid = threadIdx.x;
    if (tid < 128) { sNeI[tid] = ne[i0 + tid]; sNI[tid] = nrm[i0 + tid]; }
    else { sNeJ[tid - 128] = ne[j0 + tid - 128]; sNJ[tid - 128] = nrm[j0 + tid - 128]; }
    __syncthreads();

    int wave = tid >> 6, lane = tid & 63;
    int m = lane & 15, quad = lane >> 4;
    int wi = wave & 1, wj = wave >> 1;
    int rtA = (i0 >> 4) + wi * 4;            // + im
    int rtB = (j0 >> 4) + wj * 4;            // + jn
    size_t loH = (size_t)(m * 32 + quad * 8);   // halfs (E frags)
    size_t loB = (size_t)(m * 64 + quad * 16);  // bytes (V fp8 frags)

    // ---- G phase: K=512, 8 chunks of 64; fp8, no LDS, no barriers ----
    f32x4 gacc[4][4] = {};
    for (int c = 0; c < 8; ++c) {
        l2t a[4], b[4];
#pragma unroll
        for (int im = 0; im < 4; ++im)
            a[im] = *(const l2t*)(VF8 + (((size_t)(rtA + im) * 8 + c) << 10) + loB);
#pragma unroll
        for (int jn = 0; jn < 4; ++jn)
            b[jn] = *(const l2t*)(VF8 + (((size_t)(rtB + jn) * 8 + c) << 10) + loB);
#pragma unroll
        for (int jn = 0; jn < 4; ++jn)
#pragma unroll
            for (int im = 0; im < 4; ++im) {
                gacc[im][jn] = MFMA8(a[im][0], b[jn][0], gacc[im][jn]);
                gacc[im][jn] = MFMA8(a[im][1], b[jn][1], gacc[im][jn]);
            }
    }

    // ---- fused S phase + epilogue (plain fp16, B-frags hoisted) ----
    half8 bh[4][2];
#pragma unroll
    for (int jn = 0; jn < 4; ++jn) {
        size_t bb = (size_t)(rtB + jn) * 2 * 512 + loH;
        bh[jn][0] = *(const half8*)(EFh + bb);
        bh[jn][1] = *(const half8*)(EFh + bb + 512);
    }
    float zj[4] = {}, nj_[4] = {};
#pragma unroll
    for (int im = 0; im < 4; ++im) {
        size_t ab = (size_t)(rtA + im) * 2 * 512 + loH;
        half8 ah0 = *(const half8*)(EFh + ab);
        half8 ah1 = *(const half8*)(EFh + ab + 512);
        f32x4 zi4 = {0.f, 0.f, 0.f, 0.f};
        f32x4 ni4 = {0.f, 0.f, 0.f, 0.f};
#pragma unroll
        for (int jn = 0; jn < 4; ++jn) {
            f32x4 acc = {0.f, 0.f, 0.f, 0.f};
            acc = MFMA16(ah0, bh[jn][0], acc);
            acc = MFMA16(ah1, bh[jn][1], acc);
            int jl = (wj << 6) + jn * 16 + m;
            int jg = j0 + jl;
            float nej = sNeJ[jl], nnj = sNJ[jl];
            f32x4 g4 = gacc[im][jn];
            bool p[4];
            bool anyp = false;
#pragma unroll
            for (int r = 0; r < 4; ++r) {
                int il = (wi << 6) + im * 16 + quad * 4 + r;
                int ig = i0 + il;
                float nei = sNeI[il];
                p[r] = (acc[r] > fminf(nei, nej) - SEL_T) && (!diag || ig < jg);
                anyp |= p[r];
            }
            if (__builtin_amdgcn_ballot_w64(anyp)) {   // wave-uniform skip
#pragma unroll
                for (int r = 0; r < 4; ++r) {
                    if (p[r]) {
                        int il = (wi << 6) + im * 16 + quad * 4 + r;
                        float nei = sNeI[il], nni = sNI[il];
                        float s = acc[r];
                        float wiw = __expf(s - nei);
                        float wjw = __expf(s - nej);
                        float wd = nni + nnj - 2.f * g4[r];
                        zi4[r] += wiw;  ni4[r] += wiw * wd;
                        zj[jn] += wjw;  nj_[jn] += wjw * wd;
                    }
                }
            }
        }
        // i-side: reduce over 16 m-lanes, write wj-plane
#pragma unroll
        for (int msk = 1; msk < 16; msk <<= 1) {
#pragma unroll
            for (int r = 0; r < 4; ++r) {
                zi4[r] += __shfl_xor(zi4[r], msk, 64);
                ni4[r] += __shfl_xor(ni4[r], msk, 64);
            }
        }
        if (m == 0) {
            int row0 = (wi << 6) + im * 16 + quad * 4;
            *(f32x4*)(scr + (wj << 7) + row0)       = zi4;
            *(f32x4*)(scr + 256 + (wj << 7) + row0) = ni4;
        }
    }
    // j-side: reduce over quads, write wi-plane
#pragma unroll
    for (int msk = 16; msk < 64; msk <<= 1) {
#pragma unroll
        for (int jn = 0; jn < 4; ++jn) {
            zj[jn]  += __shfl_xor(zj[jn],  msk, 64);
            nj_[jn] += __shfl_xor(nj_[jn], msk, 64);
        }
    }
    if (quad == 0) {
#pragma unroll
        for (int jn = 0; jn < 4; ++jn) {
            int jl = (wj << 6) + jn * 16 + m;
            scr[512 + (wi << 7) + jl] = zj[jn];
            scr[768 + (wi << 7) + jl] = nj_[jn];
        }
    }
    __syncthreads();
    // fold planes -> direct device atomics (zero-skip for empty rows)
    if (tid < 128) {
        float az = scr[tid]       + scr[128 + tid];
        float an = scr[256 + tid] + scr[384 + tid];
        if (az != 0.f || an != 0.f) {
            atomicAdd(Z + i0 + tid,   az);
            atomicAdd(num + i0 + tid, an);
        }
    } else {
        int cidx = tid - 128;
        float az = scr[512 + cidx] + scr[640 + cidx];
        float an = scr[768 + cidx] + scr[896 + cidx];
        if (az != 0.f || an != 0.f) {
            atomicAdd(Z + j0 + cidx,   az);
            atomicAdd(num + j0 + cidx, an);
        }
    }

    // ---- completion counter: last block does the final reduce ----
    __syncthreads();                 // all atomics drained (vmcnt(0) @ barrier)
    if (tid == 0) {
        __threadfence();
        unsigned old = atomicAdd(cnt, 1u);
        lastFlag = (old == 2079u) ? 1u : 0u;
    }
    __syncthreads();
    if (lastFlag) {
        double acc = 0.0;
#pragma unroll
        for (int k = 0; k < 32; ++k) {
            int r = (k << 8) + tid;
            float z  = atomicAdd(Z + r, 0.0f);     // fresh device-scope read
            float nv = atomicAdd(num + r, 0.0f);
            acc += (double)nv / (double)z;
        }
        double* sd = (double*)scr;
        sd[tid] = acc;
        __syncthreads();
        for (int st = 128; st > 0; st >>= 1) {
            if (tid < st) sd[tid] += sd[tid + st];
            __syncthreads();
        }
        if (tid == 0) out[0] = (float)(sd[0] / 67108864.0);   // / B^2
    }
}

// ---------------- host launcher -----------------------------------------
extern "C" void kernel_launch(void* const* d_in, const int* in_sizes, int n_in,
                              void* d_out, int out_size, void* d_ws, size_t ws_size,
                              hipStream_t stream) {
    const float* V = (const float*)d_in[0];   // [8192, 512] f32
    const float* E = (const float*)d_in[1];   // [8192, 64]  f32
    float* out = (float*)d_out;
    char* ws = (char*)d_ws;

    float*         n_   = (float*)(ws + 0);            // 32 KB
    float*         ne   = (float*)(ws + 32768);        // 32 KB
    float*         Z    = (float*)(ws + 65536);        // 32 KB (init 1 in k_prep)
    float*         num  = (float*)(ws + 98304);        // 32 KB (init 0 in k_prep)
    unsigned char* VF8  = (unsigned char*)(ws + 131072);// 4 MB fp8 V frags
    _Float16*      EFh  = (_Float16*)(ws + 4325376);   // 1 MB
    unsigned*      cnt  = (unsigned*)(ws + 5373952);   // 4 B

    k_prep<<<512, 256, 0, stream>>>(V, E, n_, ne, Z, num, VF8, EFh, cnt);
    k_mega<<<2080, 256, 0, stream>>>(VF8, EFh, ne, n_, Z, num, cnt, out);
}

// Round 16
// 139.032 us; speedup vs baseline: 1.5003x; 1.3188x over previous
//
#include <hip/hip_runtime.h>

// TangentSpaceLoss: loss = (1/B^2) sum_ij softmax_j(E E^T)_ij * ||v_i - v_j||^2
// B=8192, G=512, D=64.
//
// R15 post-mortem: merged last-block reduce cost 42us inside k_mega (static
// reg-pressure spill ~16B/thread + per-block threadfence) while saving only
// ~13us -> REVERTED to R13's 3-launch structure (best known: 135us).
// R16 adds ONE change: manual register double-buffer in the G K-loop
// (prefetch chunk c+1's 8 fragments while chunk c's 32 MFMAs execute).
// Peak regs ~148 (gacc 64 AGPR + 2x32 VGPR frag buffers + epilogue) ->
// still 3 waves/SIMD, no spill expected (tripwire: WRITE >> 14 MB).
//   G: fp8 e4m3 MFMA K=512 (VF8 frag-linear, 16B/lane wave-loads, no LDS
//      staging, no barriers in the K-loop, reg-dbuf pipelined)
//   S: fp16 MFMA (EFh frag-linear, B-frags hoisted), fused epilogue w/
//      ballot-skip, LDS-plane cross-wave combine, direct Z/num atomics.
// Selection: s > min(ne_i,ne_j)-32 (safe superset). Softmax shift ne_i;
// diagonal w=1, wd=0 -> Z preinit 1 (k_prep). XCD band swizzle (2080=8*260).
//
// VF8: [rt 512][c 8][m 16][q 4][kc 2][8B]; lane (m,quad) reads 16B at
// m*64+quad*16 (bytes 0-7 = K-chunk kc0, 8-15 = kc1).
// EFh: [rt 512][kc 2][m 16][k' 32] halfs.

#define SEL_T 32.0f

typedef _Float16 half8 __attribute__((ext_vector_type(8)));
typedef float    f32x4 __attribute__((ext_vector_type(4)));
typedef long     l2t   __attribute__((ext_vector_type(2)));

#define MFMA16(a, b, c) __builtin_amdgcn_mfma_f32_16x16x32_f16(a, b, c, 0, 0, 0)
#define MFMA8(a, b, c)  __builtin_amdgcn_mfma_f32_16x16x32_fp8_fp8(a, b, c, 0, 0, 0)

// ---------------- K1: norms + fp8 V + fp16 E layouts + Z/num init -------
__global__ __launch_bounds__(256) void k_prep(
    const float* __restrict__ V, const float* __restrict__ E,
    float* __restrict__ n, float* __restrict__ ne,
    float* __restrict__ Z, float* __restrict__ num,
    unsigned char* __restrict__ VF8, _Float16* __restrict__ EFh,
    unsigned* __restrict__ cnt) {
    int rt = blockIdx.x;                       // 512 row-tiles of 16 rows
    int tid = threadIdx.x, wave = tid >> 6, lane = tid & 63;
    if (rt == 0 && tid == 0) *cnt = 0;
    int m = lane >> 2, q = lane & 3;
    int row = rt * 16 + m;
    const float* vr = V + (size_t)row * 512;
    float sn = 0.f;
#pragma unroll
    for (int it = 0; it < 2; ++it) {
        int c = wave + it * 4;                 // K-chunk of 64
        const float4* p0 = (const float4*)(vr + c * 64 + q * 8);
        const float4* p1 = (const float4*)(vr + c * 64 + 32 + q * 8);
        float4 a0 = p0[0], a1 = p0[1], b0 = p1[0], b1 = p1[1];
        int w0 = 0, w1 = 0, w2 = 0, w3 = 0;
        w0 = __builtin_amdgcn_cvt_pk_fp8_f32(a0.x, a0.y, w0, false);
        w0 = __builtin_amdgcn_cvt_pk_fp8_f32(a0.z, a0.w, w0, true);
        w1 = __builtin_amdgcn_cvt_pk_fp8_f32(a1.x, a1.y, w1, false);
        w1 = __builtin_amdgcn_cvt_pk_fp8_f32(a1.z, a1.w, w1, true);
        w2 = __builtin_amdgcn_cvt_pk_fp8_f32(b0.x, b0.y, w2, false);
        w2 = __builtin_amdgcn_cvt_pk_fp8_f32(b0.z, b0.w, w2, true);
        w3 = __builtin_amdgcn_cvt_pk_fp8_f32(b1.x, b1.y, w3, false);
        w3 = __builtin_amdgcn_cvt_pk_fp8_f32(b1.z, b1.w, w3, true);
        uint4 o;
        o.x = (unsigned)w0; o.y = (unsigned)w1;
        o.z = (unsigned)w2; o.w = (unsigned)w3;
        *(uint4*)(VF8 + (((size_t)rt * 8 + c) << 10) + lane * 16) = o;
        sn += a0.x*a0.x + a0.y*a0.y + a0.z*a0.z + a0.w*a0.w
            + a1.x*a1.x + a1.y*a1.y + a1.z*a1.z + a1.w*a1.w
            + b0.x*b0.x + b0.y*b0.y + b0.z*b0.z + b0.w*b0.w
            + b1.x*b1.x + b1.y*b1.y + b1.z*b1.z + b1.w*b1.w;
    }
    __shared__ float sred[4][64];
    sred[wave][lane] = sn;
    __syncthreads();
    if (tid < 16) {
        float s = 0.f;
#pragma unroll
        for (int w = 0; w < 4; ++w)
#pragma unroll
            for (int qq = 0; qq < 4; ++qq) s += sred[w][tid * 4 + qq];
        int rr = rt * 16 + tid;
        n[rr] = s;
        Z[rr] = 1.0f;                          // diagonal w=1, wd=0
        num[rr] = 0.0f;
    }
    // E: threads 0..127: rl = t>>3, u = t&7, k in [u*8, u*8+8)
    if (tid < 128) {
        int rl = tid >> 3, u = tid & 7;
        int erow = rt * 16 + rl;
        const float4* er = (const float4*)(E + (size_t)erow * 64);
        float4 x0 = er[u * 2], x1 = er[u * 2 + 1];
        float xf[8] = {x0.x, x0.y, x0.z, x0.w, x1.x, x1.y, x1.z, x1.w};
        half8 h;
        float se = 0.f;
#pragma unroll
        for (int k = 0; k < 8; ++k) {
            h[k] = (_Float16)xf[k];
            se += xf[k] * xf[k];
        }
        int kc = u >> 2, qq = u & 3;
        *(half8*)(EFh + ((size_t)rt * 2 + kc) * 512 + rl * 32 + qq * 8) = h;
        se += __shfl_xor(se, 1, 64);
        se += __shfl_xor(se, 2, 64);
        se += __shfl_xor(se, 4, 64);
        if (u == 0) ne[erow] = se;
    }
}

// ---------------- K2: zero-LDS gather tile kernel -----------------------
// 256 thr = 4 waves in 2x2 grid; wave tile 64x64 = 4x4 MFMA tiles.
__global__ __launch_bounds__(256, 3) void k_mega(
    const unsigned char* __restrict__ VF8, const _Float16* __restrict__ EFh,
    const float* __restrict__ ne, const float* __restrict__ nrm,
    float* __restrict__ Z, float* __restrict__ num) {
    // XCD band swizzle + triangular decode: blk -> (bx <= by)
    int blk0 = blockIdx.x;
    int blk = (blk0 & 7) * 260 + (blk0 >> 3);
    int by = (int)((sqrtf(8.f * (float)blk + 1.f) - 1.f) * 0.5f);
    while ((by + 1) * (by + 2) / 2 <= blk) ++by;
    while (by * (by + 1) / 2 > blk) --by;
    int bx = blk - by * (by + 1) / 2;
    int i0 = bx << 7, j0 = by << 7;
    bool diag = (bx == by);

    __shared__ float sNeI[128], sNeJ[128], sNI[128], sNJ[128];
    __shared__ __align__(16) float scr[1024];

    int tid = threadIdx.x;
    if (tid < 128) { sNeI[tid] = ne[i0 + tid]; sNI[tid] = nrm[i0 + tid]; }
    else { sNeJ[tid - 128] = ne[j0 + tid - 128]; sNJ[tid - 128] = nrm[j0 + tid - 128]; }
    __syncthreads();

    int wave = tid >> 6, lane = tid & 63;
    int m = lane & 15, quad = lane >> 4;
    int wi = wave & 1, wj = wave >> 1;
    int rtA = (i0 >> 4) + wi * 4;            // + im
    int rtB = (j0 >> 4) + wj * 4;            // + jn
    size_t loH = (size_t)(m * 32 + quad * 8);   // halfs (E frags)
    size_t loB = (size_t)(m * 64 + quad * 16);  // bytes (V fp8 frags)

    const unsigned char* pA = VF8 + (((size_t)rtA * 8) << 10) + loB;
    const unsigned char* pB = VF8 + (((size_t)rtB * 8) << 10) + loB;
    // frag(im, c) at pA + im*8192 + c*1024

    // ---- G phase: K=512, 8 chunks of 64; fp8, reg-dbuf pipelined ----
    f32x4 gacc[4][4] = {};
    l2t a0[4], b0[4], a1[4], b1[4];
#pragma unroll
    for (int im = 0; im < 4; ++im) a0[im] = *(const l2t*)(pA + im * 8192);
#pragma unroll
    for (int jn = 0; jn < 4; ++jn) b0[jn] = *(const l2t*)(pB + jn * 8192);
#pragma unroll
    for (int c = 0; c < 8; c += 2) {
        // prefetch chunk c+1 while computing chunk c
#pragma unroll
        for (int im = 0; im < 4; ++im)
            a1[im] = *(const l2t*)(pA + im * 8192 + (c + 1) * 1024);
#pragma unroll
        for (int jn = 0; jn < 4; ++jn)
            b1[jn] = *(const l2t*)(pB + jn * 8192 + (c + 1) * 1024);
#pragma unroll
        for (int jn = 0; jn < 4; ++jn)
#pragma unroll
            for (int im = 0; im < 4; ++im) {
                gacc[im][jn] = MFMA8(a0[im][0], b0[jn][0], gacc[im][jn]);
                gacc[im][jn] = MFMA8(a0[im][1], b0[jn][1], gacc[im][jn]);
            }
        // prefetch chunk c+2 while computing chunk c+1
        if (c + 2 < 8) {
#pragma unroll
            for (int im = 0; im < 4; ++im)
                a0[im] = *(const l2t*)(pA + im * 8192 + (c + 2) * 1024);
#pragma unroll
            for (int jn = 0; jn < 4; ++jn)
                b0[jn] = *(const l2t*)(pB + jn * 8192 + (c + 2) * 1024);
        }
#pragma unroll
        for (int jn = 0; jn < 4; ++jn)
#pragma unroll
            for (int im = 0; im < 4; ++im) {
                gacc[im][jn] = MFMA8(a1[im][0], b1[jn][0], gacc[im][jn]);
                gacc[im][jn] = MFMA8(a1[im][1], b1[jn][1], gacc[im][jn]);
            }
    }

    // ---- fused S phase + epilogue (plain fp16, B-frags hoisted) ----
    half8 bh[4][2];
#pragma unroll
    for (int jn = 0; jn < 4; ++jn) {
        size_t bb = (size_t)(rtB + jn) * 2 * 512 + loH;
        bh[jn][0] = *(const half8*)(EFh + bb);
        bh[jn][1] = *(const half8*)(EFh + bb + 512);
    }
    float zj[4] = {}, nj_[4] = {};
#pragma unroll
    for (int im = 0; im < 4; ++im) {
        size_t ab = (size_t)(rtA + im) * 2 * 512 + loH;
        half8 ah0 = *(const half8*)(EFh + ab);
        half8 ah1 = *(const half8*)(EFh + ab + 512);
        f32x4 zi4 = {0.f, 0.f, 0.f, 0.f};
        f32x4 ni4 = {0.f, 0.f, 0.f, 0.f};
#pragma unroll
        for (int jn = 0; jn < 4; ++jn) {
            f32x4 acc = {0.f, 0.f, 0.f, 0.f};
            acc = MFMA16(ah0, bh[jn][0], acc);
            acc = MFMA16(ah1, bh[jn][1], acc);
            int jl = (wj << 6) + jn * 16 + m;
            int jg = j0 + jl;
            float nej = sNeJ[jl], nnj = sNJ[jl];
            f32x4 g4 = gacc[im][jn];
            bool p[4];
            bool anyp = false;
#pragma unroll
            for (int r = 0; r < 4; ++r) {
                int il = (wi << 6) + im * 16 + quad * 4 + r;
                int ig = i0 + il;
                float nei = sNeI[il];
                p[r] = (acc[r] > fminf(nei, nej) - SEL_T) && (!diag || ig < jg);
                anyp |= p[r];
            }
            if (__builtin_amdgcn_ballot_w64(anyp)) {   // wave-uniform skip
#pragma unroll
                for (int r = 0; r < 4; ++r) {
                    if (p[r]) {
                        int il = (wi << 6) + im * 16 + quad * 4 + r;
                        float nei = sNeI[il], nni = sNI[il];
                        float s = acc[r];
                        float wiw = __expf(s - nei);
                        float wjw = __expf(s - nej);
                        float wd = nni + nnj - 2.f * g4[r];
                        zi4[r] += wiw;  ni4[r] += wiw * wd;
                        zj[jn] += wjw;  nj_[jn] += wjw * wd;
                    }
                }
            }
        }
        // i-side: reduce over 16 m-lanes, write wj-plane
#pragma unroll
        for (int msk = 1; msk < 16; msk <<= 1) {
#pragma unroll
            for (int r = 0; r < 4; ++r) {
                zi4[r] += __shfl_xor(zi4[r], msk, 64);
                ni4[r] += __shfl_xor(ni4[r], msk, 64);
            }
        }
        if (m == 0) {
            int row0 = (wi << 6) + im * 16 + quad * 4;
            *(f32x4*)(scr + (wj << 7) + row0)       = zi4;
            *(f32x4*)(scr + 256 + (wj << 7) + row0) = ni4;
        }
    }
    // j-side: reduce over quads, write wi-plane
#pragma unroll
    for (int msk = 16; msk < 64; msk <<= 1) {
#pragma unroll
        for (int jn = 0; jn < 4; ++jn) {
            zj[jn]  += __shfl_xor(zj[jn],  msk, 64);
            nj_[jn] += __shfl_xor(nj_[jn], msk, 64);
        }
    }
    if (quad == 0) {
#pragma unroll
        for (int jn = 0; jn < 4; ++jn) {
            int jl = (wj << 6) + jn * 16 + m;
            scr[512 + (wi << 7) + jl] = zj[jn];
            scr[768 + (wi << 7) + jl] = nj_[jn];
        }
    }
    __syncthreads();
    // fold planes -> direct device atomics (zero-skip for empty rows)
    if (tid < 128) {
        float az = scr[tid]       + scr[128 + tid];
        float an = scr[256 + tid] + scr[384 + tid];
        if (az != 0.f || an != 0.f) {
            atomicAdd(Z + i0 + tid,   az);
            atomicAdd(num + i0 + tid, an);
        }
    } else {
        int cidx = tid - 128;
        float az = scr[512 + cidx] + scr[640 + cidx];
        float an = scr[768 + cidx] + scr[896 + cidx];
        if (az != 0.f || an != 0.f) {
            atomicAdd(Z + j0 + cidx,   az);
            atomicAdd(num + j0 + cidx, an);
        }
    }
}

// ------- K3: trivial 8192-row reduce + last-block final fold ------------
__global__ __launch_bounds__(256) void k_red(
    const float* __restrict__ Z, const float* __restrict__ num,
    double* __restrict__ part, unsigned* __restrict__ cnt,
    float* __restrict__ out) {
    int r = (blockIdx.x << 8) + threadIdx.x;   // 32 blocks x 256 threads
    __shared__ double sd[256];
    sd[threadIdx.x] = (double)num[r] / (double)Z[r];
    __syncthreads();
    for (int st = 128; st > 0; st >>= 1) {
        if (threadIdx.x < st) sd[threadIdx.x] += sd[threadIdx.x + st];
        __syncthreads();
    }
    if (threadIdx.x == 0) {
        part[blockIdx.x] = sd[0];
        __threadfence();
        unsigned old = atomicAdd(cnt, 1u);
        if (old == 31u) {                // last block folds
            __threadfence();
            double a = 0.0;
            for (int k = 0; k < 32; ++k) a += part[k];
            out[0] = (float)(a / 67108864.0);   // / B^2
        }
    }
}

// ---------------- host launcher -----------------------------------------
extern "C" void kernel_launch(void* const* d_in, const int* in_sizes, int n_in,
                              void* d_out, int out_size, void* d_ws, size_t ws_size,
                              hipStream_t stream) {
    const float* V = (const float*)d_in[0];   // [8192, 512] f32
    const float* E = (const float*)d_in[1];   // [8192, 64]  f32
    float* out = (float*)d_out;
    char* ws = (char*)d_ws;

    float*         n_   = (float*)(ws + 0);            // 32 KB
    float*         ne   = (float*)(ws + 32768);        // 32 KB
    float*         Z    = (float*)(ws + 65536);        // 32 KB (init 1 in k_prep)
    float*         num  = (float*)(ws + 98304);        // 32 KB (init 0 in k_prep)
    unsigned char* VF8  = (unsigned char*)(ws + 131072);// 4 MB fp8 V frags
    _Float16*      EFh  = (_Float16*)(ws + 4325376);   // 1 MB
    double*        part = (double*)(ws + 5373952);     // 256 B
    unsigned*      cnt  = (unsigned*)(ws + 5374208);   // 4 B

    k_prep<<<512, 256, 0, stream>>>(V, E, n_, ne, Z, num, VF8, EFh, cnt);
    k_mega<<<2080, 256, 0, stream>>>(VF8, EFh, ne, n_, Z, num);
    k_red <<<32, 256, 0, stream>>>(Z, num, part, cnt, out);
}